// Round 6
// baseline (241.991 us; speedup 1.0000x reference)
//
#include <hip/hip_runtime.h>
#include <stdint.h>

// y[m][n] = sum_k x[m][k] * W[k][n] + b[n]
// M=262144, K=128, N=128. 268 MB @ ~6.3 TB/s ~= 43 us floor.
//
// R6: AMORTIZE W-STAGING. Evidence: R0-R5 varied store type, load/store
// coalescing, occupancy (17-33%), prefetch — all ~no effect, pinned ~83 us,
// all pipes <10%. The one constant: every block re-reads the full 64 KB fp32
// W with 64 column-strided scalar loads + ~192 VALU f2bf per THREAD before a
// barrier (128 MB L2 traffic, 33M scalar loads total).
// Fix: kernel prep_w builds the bf16 A-fragment image of W ONCE into d_ws
// (32 KB); the main kernel pulls it into LDS with 8 global_load_lds per wave
// (L2-hot, zero VALU) instead. Everything else = R4 structure (scattered
// f32x4 x loads + prefetch fences, MFMA, direct cached f32x4 stores — all
// proven correct/equivalent-speed).

typedef __attribute__((ext_vector_type(8))) short bf16x8;   // 8 bf16 = 4 VGPRs
typedef __attribute__((ext_vector_type(4))) float f32x4;    // MFMA C/D

__device__ inline unsigned short f2bf(float f) {
  // round-to-nearest-even fp32 -> bf16 (inputs are finite normals)
  union { float f; uint32_t u; } v; v.f = f;
  uint32_t r = v.u + 0x7fffu + ((v.u >> 16) & 1u);
  return (unsigned short)(r >> 16);
}

__device__ inline bf16x8 cvt8(f32x4 a, f32x4 b) {
  bf16x8 r;
  r[0] = f2bf(a[0]); r[1] = f2bf(a[1]); r[2] = f2bf(a[2]); r[3] = f2bf(a[3]);
  r[4] = f2bf(b[0]); r[5] = f2bf(b[1]); r[6] = f2bf(b[2]); r[7] = f2bf(b[3]);
  return r;
}

__device__ inline void gload_lds16(const void* g, void* l) {
  __builtin_amdgcn_global_load_lds(
      (const __attribute__((address_space(1))) unsigned int*)g,
      (__attribute__((address_space(3))) unsigned int*)l, 16, 0, 0);
}

// ---- one-time: W (fp32 [128][128]) -> bf16 A-fragment image in workspace.
// Layout identical to prior rounds' lds_w:
//   ws[(g)*8 + j] = f2bf(W[kk*32+qk*8+j][nt*16+lc]),
//   g = (kk*8+nt)*64 + qk*16+lc
__global__ void prep_w(const float* __restrict__ w,
                       unsigned short* __restrict__ wfrag) {
  int g = blockIdx.x * 256 + threadIdx.x;   // 8 blocks x 256 = 2048 groups
  int fragid = g >> 6;             // kk*8+nt
  int slot   = g & 63;             // qk*16+lc
  int kk = fragid >> 3, nt = fragid & 7;
  int qk = slot >> 4,   lc = slot & 15;
  const float* wp = w + (size_t)(kk * 32 + qk * 8) * 128 + nt * 16 + lc;
  unsigned short tmp[8];
  #pragma unroll
  for (int j = 0; j < 8; ++j) tmp[j] = f2bf(wp[(size_t)j * 128]);
  *(bf16x8*)&wfrag[(size_t)g * 8] = *(const bf16x8*)tmp;
}

__global__ __launch_bounds__(256, 4) void linear_kernel(
    const float* __restrict__ x, const unsigned short* __restrict__ wfrag,
    const float* __restrict__ bias, float* __restrict__ y) {
  __shared__ __align__(16) unsigned short lds_w[128 * 128];  // 32 KB

  const int t = threadIdx.x;
  const int lane = t & 63;
  const int wave = t >> 6;
  const int col  = lane & 15;                  // y-row within 16-row tile
  const int quad = lane >> 4;

  // 256 rows per block: 4 iters x 64 rows (16 rows/wave/iter)
  const size_t row0 = (size_t)blockIdx.x * 256 + wave * 16 + col;
  const float* xp = x + row0 * 128 + quad * 8;

  // ---- issue iter-0 x loads first (long-latency HBM; oldest in queue) ----
  f32x4 buf[8];
  #pragma unroll
  for (int kk = 0; kk < 4; ++kk) {
    buf[2 * kk]     = *(const f32x4*)(xp + kk * 32);
    buf[2 * kk + 1] = *(const f32x4*)(xp + kk * 32 + 4);
  }
  __builtin_amdgcn_sched_barrier(0);

  // ---- W fragment image -> LDS: 8 DMA per wave, L2-hot, zero VALU ----
  #pragma unroll
  for (int i = 0; i < 8; ++i) {
    int seg = wave * 8 + i;                       // 1 KB segment id (0..31)
    gload_lds16(wfrag + (size_t)seg * 512 + lane * 8, &lds_w[(size_t)seg * 512]);
  }

  // bias fragment: lane's 4 outputs are y cols nt*16 + quad*4 .. +3
  f32x4 bfrag[8];
  #pragma unroll
  for (int nt = 0; nt < 8; ++nt)
    bfrag[nt] = *(const f32x4*)(bias + nt * 16 + quad * 4);

  asm volatile("s_waitcnt vmcnt(0)" ::: "memory");  // drain DMA + iter-0 loads
  __syncthreads();                                  // lds_w visible block-wide

  // convert iter-0
  bf16x8 xf[4];
  #pragma unroll
  for (int kk = 0; kk < 4; ++kk) xf[kk] = cvt8(buf[2 * kk], buf[2 * kk + 1]);

  #pragma unroll
  for (int it = 0; it < 4; ++it) {
    // ---- issue next iter's loads; stay in flight under MFMA+stores ----
    if (it < 3) {
      const float* xpn = xp + (size_t)(it + 1) * 64 * 128;
      #pragma unroll
      for (int kk = 0; kk < 4; ++kk) {
        buf[2 * kk]     = *(const f32x4*)(xpn + kk * 32);
        buf[2 * kk + 1] = *(const f32x4*)(xpn + kk * 32 + 4);
      }
    }
    __builtin_amdgcn_sched_barrier(0);

    // ---- compute + store current iter ----
    float* ypi = y + (row0 + (size_t)it * 64) * 128;
    #pragma unroll
    for (int nt = 0; nt < 8; ++nt) {
      f32x4 acc = bfrag[nt];
      #pragma unroll
      for (int kk = 0; kk < 4; ++kk) {
        bf16x8 wf = *(const bf16x8*)&lds_w[((kk * 8 + nt) * 64 + lane) * 8];
        // D = (W tile)^T . (x tile)^T : D[m][n] = y[row+n][nt*16+m]
        acc = __builtin_amdgcn_mfma_f32_16x16x32_bf16(wf, xf[kk], acc, 0, 0, 0);
      }
      // cached f32x4: lanes {c,c+16,c+32,c+48} fill whole 64B sectors
      *(f32x4*)(ypi + nt * 16 + quad * 4) = acc;
    }
    __builtin_amdgcn_sched_barrier(0);

    // ---- wait on prefetched loads, convert for next iter ----
    if (it < 3) {
      #pragma unroll
      for (int kk = 0; kk < 4; ++kk) xf[kk] = cvt8(buf[2 * kk], buf[2 * kk + 1]);
    }
  }
}

// ---- fallback (ws unavailable): R4 kernel, self-staging ----
__global__ __launch_bounds__(256, 4) void linear_fallback(
    const float* __restrict__ x, const float* __restrict__ w,
    const float* __restrict__ bias, float* __restrict__ y) {
  __shared__ __align__(16) unsigned short lds_w[128 * 128];
  const int t = threadIdx.x;
  const int lane = t & 63, wave = t >> 6;
  const int col = lane & 15, quad = lane >> 4;
  const size_t row0 = (size_t)blockIdx.x * 256 + wave * 16 + col;
  const float* xp = x + row0 * 128 + quad * 8;
  f32x4 buf[8];
  #pragma unroll
  for (int kk = 0; kk < 4; ++kk) {
    buf[2 * kk]     = *(const f32x4*)(xp + kk * 32);
    buf[2 * kk + 1] = *(const f32x4*)(xp + kk * 32 + 4);
  }
  #pragma unroll
  for (int gi = 0; gi < 8; ++gi) {
    int g = t + 256 * gi;
    int fragid = g >> 6, slot = g & 63;
    int kk = fragid >> 3, nt = fragid & 7;
    int qk = slot >> 4, lc = slot & 15;
    const float* wp = w + (size_t)(kk * 32 + qk * 8) * 128 + nt * 16 + lc;
    unsigned short tmp[8];
    #pragma unroll
    for (int j = 0; j < 8; ++j) tmp[j] = f2bf(wp[(size_t)j * 128]);
    *(bf16x8*)&lds_w[(size_t)g * 8] = *(const bf16x8*)tmp;
  }
  f32x4 bfrag[8];
  #pragma unroll
  for (int nt = 0; nt < 8; ++nt)
    bfrag[nt] = *(const f32x4*)(bias + nt * 16 + quad * 4);
  __syncthreads();
  bf16x8 xf[4];
  #pragma unroll
  for (int kk = 0; kk < 4; ++kk) xf[kk] = cvt8(buf[2 * kk], buf[2 * kk + 1]);
  #pragma unroll
  for (int it = 0; it < 4; ++it) {
    if (it < 3) {
      const float* xpn = xp + (size_t)(it + 1) * 64 * 128;
      #pragma unroll
      for (int kk = 0; kk < 4; ++kk) {
        buf[2 * kk]     = *(const f32x4*)(xpn + kk * 32);
        buf[2 * kk + 1] = *(const f32x4*)(xpn + kk * 32 + 4);
      }
    }
    __builtin_amdgcn_sched_barrier(0);
    float* ypi = y + (row0 + (size_t)it * 64) * 128;
    #pragma unroll
    for (int nt = 0; nt < 8; ++nt) {
      f32x4 acc = bfrag[nt];
      #pragma unroll
      for (int kk = 0; kk < 4; ++kk) {
        bf16x8 wf = *(const bf16x8*)&lds_w[((kk * 8 + nt) * 64 + lane) * 8];
        acc = __builtin_amdgcn_mfma_f32_16x16x32_bf16(wf, xf[kk], acc, 0, 0, 0);
      }
      *(f32x4*)(ypi + nt * 16 + quad * 4) = acc;
    }
    __builtin_amdgcn_sched_barrier(0);
    if (it < 3) {
      #pragma unroll
      for (int kk = 0; kk < 4; ++kk) xf[kk] = cvt8(buf[2 * kk], buf[2 * kk + 1]);
    }
  }
}

extern "C" void kernel_launch(void* const* d_in, const int* in_sizes, int n_in,
                              void* d_out, int out_size, void* d_ws, size_t ws_size,
                              hipStream_t stream) {
  const float* x    = (const float*)d_in[0];
  const float* w    = (const float*)d_in[1];
  const float* bias = (const float*)d_in[2];
  float* y = (float*)d_out;
  if (d_ws && ws_size >= 32768) {
    unsigned short* wfrag = (unsigned short*)d_ws;
    prep_w<<<8, 256, 0, stream>>>(w, wfrag);
    linear_kernel<<<1024, 256, 0, stream>>>(x, wfrag, bias, y);
  } else {
    linear_fallback<<<1024, 256, 0, stream>>>(x, w, bias, y);
  }
}